// Round 2
// baseline (144.363 us; speedup 1.0000x reference)
//
#include <hip/hip_runtime.h>

#define SAMPLE_S 5

__global__ void init_out_kernel(float* out) {
    if (threadIdx.x == 0) {
        out[0] = 0.0f;
        out[1] = 0.0f;
    }
}

__device__ __forceinline__ float f4_get(const float4& v, int c) {
    switch (c) {
        case 0: return v.x;
        case 1: return v.y;
        case 2: return v.z;
        default: return v.w;
    }
}

// One (split n, row i): 5 o-values, 5 l-values.
// loss += relu(margin)*S  (diagonal)  + 2 * sum_{j<k} relu(margin - (oj-ok)*(lj-lk))
// cnt  += (argmax(o_row) == argmax(l_row))   [first-max tie semantics]
__device__ __forceinline__ void process_row(const float ox[SAMPLE_S], const float lx[SAMPLE_S],
                                            float margin, float& loss, float& cnt) {
    int po = 0, pl = 0;
    float mo = ox[0], ml = lx[0];
#pragma unroll
    for (int j = 1; j < SAMPLE_S; ++j) {
        bool bo = ox[j] > mo;   // strict > keeps FIRST max (jnp.argmax semantics)
        mo = bo ? ox[j] : mo;
        po = bo ? j : po;
        bool bl = lx[j] > ml;
        ml = bl ? lx[j] : ml;
        pl = bl ? j : pl;
    }
    if (po == pl) cnt += 1.0f;

    loss += fmaxf(margin, 0.0f) * (float)SAMPLE_S;  // j==k terms: relu(margin - 0)
#pragma unroll
    for (int j = 0; j < SAMPLE_S; ++j) {
#pragma unroll
        for (int k = j + 1; k < SAMPLE_S; ++k) {
            float t = margin - (ox[j] - ox[k]) * (lx[j] - lx[k]);
            loss += 2.0f * fmaxf(t, 0.0f);   // (j,k) and (k,j) are equal
        }
    }
}

// Grid: (ceil((N/4)/256), SAMPLE_S). blockIdx.y = row i. Each thread: 4 splits
// of one row -> 10 float4 coalesced loads (160 B/thread), ~30 waves/CU.
__global__ __launch_bounds__(256) void pml_main_kernel(
        const float* __restrict__ o, const float* __restrict__ l,
        const int* __restrict__ margin_p, float* __restrict__ out, int N) {
    const float margin = (float)(*margin_p);
    const int i = blockIdx.y;
    const long long t  = (long long)blockIdx.x * 256 + threadIdx.x;
    const long long n4 = t * 4;

    float loss = 0.0f, cnt = 0.0f;

    if (n4 + 3 < (long long)N) {
        float4 ov[SAMPLE_S], lv[SAMPLE_S];
#pragma unroll
        for (int j = 0; j < SAMPLE_S; ++j) {
            const long long base = (long long)(i * SAMPLE_S + j) * N + n4;
            ov[j] = *reinterpret_cast<const float4*>(o + base);
            lv[j] = *reinterpret_cast<const float4*>(l + base);
        }
#pragma unroll
        for (int c = 0; c < 4; ++c) {
            float ox[SAMPLE_S], lx[SAMPLE_S];
#pragma unroll
            for (int j = 0; j < SAMPLE_S; ++j) {
                ox[j] = f4_get(ov[j], c);
                lx[j] = f4_get(lv[j], c);
            }
            process_row(ox, lx, margin, loss, cnt);
        }
    } else if (n4 < (long long)N) {
        // Scalar tail (unused when N % 4 == 0, kept for generality).
        for (long long n = n4; n < (long long)N; ++n) {
            float ox[SAMPLE_S], lx[SAMPLE_S];
#pragma unroll
            for (int j = 0; j < SAMPLE_S; ++j) {
                const long long idx = (long long)(i * SAMPLE_S + j) * N + n;
                ox[j] = o[idx];
                lx[j] = l[idx];
            }
            process_row(ox, lx, margin, loss, cnt);
        }
    }

    // Wave-64 shuffle reduction, then cross-wave via LDS, one atomic pair per block.
#pragma unroll
    for (int off = 32; off > 0; off >>= 1) {
        loss += __shfl_down(loss, off, 64);
        cnt  += __shfl_down(cnt,  off, 64);
    }
    __shared__ float sl[4], sc[4];
    const int wave = threadIdx.x >> 6;
    const int lane = threadIdx.x & 63;
    if (lane == 0) { sl[wave] = loss; sc[wave] = cnt; }
    __syncthreads();
    if (threadIdx.x == 0) {
        float L = sl[0] + sl[1] + sl[2] + sl[3];
        float C = sc[0] + sc[1] + sc[2] + sc[3];
        atomicAdd(&out[0], L);
        atomicAdd(&out[1], C);
    }
}

extern "C" void kernel_launch(void* const* d_in, const int* in_sizes, int n_in,
                              void* d_out, int out_size, void* d_ws, size_t ws_size,
                              hipStream_t stream) {
    const float* o      = (const float*)d_in[0];
    const float* l      = (const float*)d_in[1];
    const int*   margin = (const int*)d_in[2];
    float*       out    = (float*)d_out;

    const int N = in_sizes[0] / (SAMPLE_S * SAMPLE_S);

    hipLaunchKernelGGL(init_out_kernel, dim3(1), dim3(64), 0, stream, out);

    const long long threads_x = ((long long)N + 3) / 4;
    const int blocks_x = (int)((threads_x + 255) / 256);
    hipLaunchKernelGGL(pml_main_kernel, dim3(blocks_x, SAMPLE_S), dim3(256), 0, stream,
                       o, l, margin, out, N);
}

// Round 3
// 105.211 us; speedup vs baseline: 1.3721x; 1.3721x over previous
//
#include <hip/hip_runtime.h>

#define SAMPLE_S 5
#define NBLOCKS  512
#define TPB      256

__device__ __forceinline__ float f4_get(const float4& v, int c) {
    switch (c) {
        case 0: return v.x;
        case 1: return v.y;
        case 2: return v.z;
        default: return v.w;
    }
}

// One (split n, row i): 5 o-values, 5 l-values.
// loss += relu(margin)*S (diagonal) + 2 * sum_{j<k} relu(margin - (oj-ok)*(lj-lk))
// cnt  += (argmax(o_row) == argmax(l_row))   [first-max tie semantics]
__device__ __forceinline__ void process_row(const float ox[SAMPLE_S], const float lx[SAMPLE_S],
                                            float margin, float& loss, float& cnt) {
    int po = 0, pl = 0;
    float mo = ox[0], ml = lx[0];
#pragma unroll
    for (int j = 1; j < SAMPLE_S; ++j) {
        bool bo = ox[j] > mo;   // strict > keeps FIRST max (jnp.argmax semantics)
        mo = bo ? ox[j] : mo;
        po = bo ? j : po;
        bool bl = lx[j] > ml;
        ml = bl ? lx[j] : ml;
        pl = bl ? j : pl;
    }
    if (po == pl) cnt += 1.0f;

    loss += fmaxf(margin, 0.0f) * (float)SAMPLE_S;  // j==k terms: relu(margin - 0)
#pragma unroll
    for (int j = 0; j < SAMPLE_S; ++j) {
#pragma unroll
        for (int k = j + 1; k < SAMPLE_S; ++k) {
            float t = margin - (ox[j] - ox[k]) * (lx[j] - lx[k]);
            loss += 2.0f * fmaxf(t, 0.0f);   // (j,k) and (k,j) are equal
        }
    }
}

// 512 equal-work blocks (2/CU, balanced under any scheduler). Each thread owns
// one float4 chunk (4 splits) and processes ALL 5 rows -> 50 coalesced float4
// loads in flight (800 B/lane), the shape that measured 3.2 TB/s even with a
// 2:1 CU imbalance. Partials go to ws (no atomics, no same-line contention).
__global__ __launch_bounds__(TPB) void pml_main_kernel(
        const float* __restrict__ o, const float* __restrict__ l,
        const int* __restrict__ margin_p, float* __restrict__ ws, int N) {
    const float margin = (float)(*margin_p);
    const int b = blockIdx.x;
    const int t = threadIdx.x;

    const int C = N >> 2;                 // number of float4 chunks
    const int q = C / NBLOCKS, r = C % NBLOCKS;
    const int cstart = b * q + (b < r ? b : r);
    const int cend   = cstart + q + (b < r ? 1 : 0);

    float loss = 0.0f, cnt = 0.0f;

    for (int c = cstart + t; c < cend; c += TPB) {
        const long long n4 = (long long)c << 2;
#pragma unroll
        for (int i = 0; i < SAMPLE_S; ++i) {
            float4 ov[SAMPLE_S], lv[SAMPLE_S];
#pragma unroll
            for (int j = 0; j < SAMPLE_S; ++j) {
                const long long base = (long long)(i * SAMPLE_S + j) * N + n4;
                ov[j] = *reinterpret_cast<const float4*>(o + base);
                lv[j] = *reinterpret_cast<const float4*>(l + base);
            }
#pragma unroll
            for (int cc = 0; cc < 4; ++cc) {
                float ox[SAMPLE_S], lx[SAMPLE_S];
#pragma unroll
                for (int j = 0; j < SAMPLE_S; ++j) {
                    ox[j] = f4_get(ov[j], cc);
                    lx[j] = f4_get(lv[j], cc);
                }
                process_row(ox, lx, margin, loss, cnt);
            }
        }
    }

    // Scalar tail for N % 4 != 0 (unused at N=400000, kept for generality).
    const int r4 = N & 3;
    if (b == 0 && t < r4) {
        const long long n = ((long long)C << 2) + t;
#pragma unroll
        for (int i = 0; i < SAMPLE_S; ++i) {
            float ox[SAMPLE_S], lx[SAMPLE_S];
#pragma unroll
            for (int j = 0; j < SAMPLE_S; ++j) {
                const long long idx = (long long)(i * SAMPLE_S + j) * N + n;
                ox[j] = o[idx];
                lx[j] = l[idx];
            }
            process_row(ox, lx, margin, loss, cnt);
        }
    }

    // Wave-64 shuffle reduction, then cross-wave via LDS; one pair of plain
    // stores per block into the workspace.
#pragma unroll
    for (int off = 32; off > 0; off >>= 1) {
        loss += __shfl_down(loss, off, 64);
        cnt  += __shfl_down(cnt,  off, 64);
    }
    __shared__ float sl[TPB / 64], sc[TPB / 64];
    const int wave = t >> 6;
    const int lane = t & 63;
    if (lane == 0) { sl[wave] = loss; sc[wave] = cnt; }
    __syncthreads();
    if (t == 0) {
        float L = 0.0f, Cc = 0.0f;
#pragma unroll
        for (int w = 0; w < TPB / 64; ++w) { L += sl[w]; Cc += sc[w]; }
        ws[b]           = L;
        ws[NBLOCKS + b] = Cc;
    }
}

// Deterministic final reduce: 512 partial pairs -> out[0], out[1].
__global__ __launch_bounds__(NBLOCKS) void pml_reduce_kernel(
        const float* __restrict__ ws, float* __restrict__ out) {
    const int t = threadIdx.x;
    float loss = ws[t];
    float cnt  = ws[NBLOCKS + t];
#pragma unroll
    for (int off = 32; off > 0; off >>= 1) {
        loss += __shfl_down(loss, off, 64);
        cnt  += __shfl_down(cnt,  off, 64);
    }
    __shared__ float sl[NBLOCKS / 64], sc[NBLOCKS / 64];
    const int wave = t >> 6;
    const int lane = t & 63;
    if (lane == 0) { sl[wave] = loss; sc[wave] = cnt; }
    __syncthreads();
    if (t == 0) {
        float L = 0.0f, Cc = 0.0f;
#pragma unroll
        for (int w = 0; w < NBLOCKS / 64; ++w) { L += sl[w]; Cc += sc[w]; }
        out[0] = L;
        out[1] = Cc;
    }
}

extern "C" void kernel_launch(void* const* d_in, const int* in_sizes, int n_in,
                              void* d_out, int out_size, void* d_ws, size_t ws_size,
                              hipStream_t stream) {
    const float* o      = (const float*)d_in[0];
    const float* l      = (const float*)d_in[1];
    const int*   margin = (const int*)d_in[2];
    float*       out    = (float*)d_out;
    float*       ws     = (float*)d_ws;

    const int N = in_sizes[0] / (SAMPLE_S * SAMPLE_S);

    hipLaunchKernelGGL(pml_main_kernel, dim3(NBLOCKS), dim3(TPB), 0, stream,
                       o, l, margin, ws, N);
    hipLaunchKernelGGL(pml_reduce_kernel, dim3(1), dim3(NBLOCKS), 0, stream,
                       ws, out);
}

// Round 6
// 104.811 us; speedup vs baseline: 1.3774x; 1.0038x over previous
//
#include <hip/hip_runtime.h>

#define SAMPLE_S 5
#define TPB      256
#define RTPB     512   // reduce kernel threads

__device__ __forceinline__ float f4_get(const float4& v, int c) {
    switch (c) {
        case 0: return v.x;
        case 1: return v.y;
        case 2: return v.z;
        default: return v.w;
    }
}

// One (split n, row i): 5 o-values, 5 l-values.
// loss += relu(margin)*S (diagonal) + 2 * sum_{j<k} relu(margin - (oj-ok)*(lj-lk))
// cnt  += (argmax(o_row) == argmax(l_row))   [first-max tie semantics]
__device__ __forceinline__ void process_row(const float ox[SAMPLE_S], const float lx[SAMPLE_S],
                                            float margin, float& loss, float& cnt) {
    int po = 0, pl = 0;
    float mo = ox[0], ml = lx[0];
#pragma unroll
    for (int j = 1; j < SAMPLE_S; ++j) {
        bool bo = ox[j] > mo;   // strict > keeps FIRST max (jnp.argmax semantics)
        mo = bo ? ox[j] : mo;
        po = bo ? j : po;
        bool bl = lx[j] > ml;
        ml = bl ? lx[j] : ml;
        pl = bl ? j : pl;
    }
    if (po == pl) cnt += 1.0f;

    loss += fmaxf(margin, 0.0f) * (float)SAMPLE_S;  // j==k terms: relu(margin - 0)
#pragma unroll
    for (int j = 0; j < SAMPLE_S; ++j) {
#pragma unroll
        for (int k = j + 1; k < SAMPLE_S; ++k) {
            float t = margin - (ox[j] - ox[k]) * (lx[j] - lx[k]);
            loss += 2.0f * fmaxf(t, 0.0f);   // (j,k) and (k,j) are equal
        }
    }
}

// Grid: (ceil((N/4)/TPB), SAMPLE_S). blockIdx.y = row i. Each thread: one
// float4 chunk (4 splits) of one row -> 10 independent coalesced float4 loads
// (160 B/lane), ~7.6 blocks/CU, all lanes active. Partials -> ws (NO atomics:
// R2 showed 3910 same-line atomics alone cost ~60 us).
__global__ __launch_bounds__(TPB) void pml_main_kernel(
        const float* __restrict__ o, const float* __restrict__ l,
        const int* __restrict__ margin_p, float* __restrict__ ws, int N) {
    const float margin = (float)(*margin_p);
    const int i = blockIdx.y;
    const int c = blockIdx.x * TPB + threadIdx.x;
    const long long n4 = (long long)c << 2;
    const int bid     = blockIdx.y * gridDim.x + blockIdx.x;

    float loss = 0.0f, cnt = 0.0f;

    if (n4 + 3 < (long long)N) {
        float4 ov[SAMPLE_S], lv[SAMPLE_S];
#pragma unroll
        for (int j = 0; j < SAMPLE_S; ++j) {
            const long long base = (long long)(i * SAMPLE_S + j) * N + n4;
            ov[j] = *reinterpret_cast<const float4*>(o + base);
            lv[j] = *reinterpret_cast<const float4*>(l + base);
        }
#pragma unroll
        for (int cc = 0; cc < 4; ++cc) {
            float ox[SAMPLE_S], lx[SAMPLE_S];
#pragma unroll
            for (int j = 0; j < SAMPLE_S; ++j) {
                ox[j] = f4_get(ov[j], cc);
                lx[j] = f4_get(lv[j], cc);
            }
            process_row(ox, lx, margin, loss, cnt);
        }
    } else if (n4 < (long long)N) {
        // Scalar tail for N % 4 != 0 (unused at N=400000, kept for generality).
        for (long long n = n4; n < (long long)N; ++n) {
            float ox[SAMPLE_S], lx[SAMPLE_S];
#pragma unroll
            for (int j = 0; j < SAMPLE_S; ++j) {
                const long long idx = (long long)(i * SAMPLE_S + j) * N + n;
                ox[j] = o[idx];
                lx[j] = l[idx];
            }
            process_row(ox, lx, margin, loss, cnt);
        }
    }

    // Wave-64 shuffle reduction, then cross-wave via LDS; one float2 store
    // per block into the workspace.
#pragma unroll
    for (int off = 32; off > 0; off >>= 1) {
        loss += __shfl_down(loss, off, 64);
        cnt  += __shfl_down(cnt,  off, 64);
    }
    __shared__ float sl[TPB / 64], sc[TPB / 64];
    const int wave = threadIdx.x >> 6;
    const int lane = threadIdx.x & 63;
    if (lane == 0) { sl[wave] = loss; sc[wave] = cnt; }
    __syncthreads();
    if (threadIdx.x == 0) {
        float L = 0.0f, Cc = 0.0f;
#pragma unroll
        for (int w = 0; w < TPB / 64; ++w) { L += sl[w]; Cc += sc[w]; }
        reinterpret_cast<float2*>(ws)[bid] = make_float2(L, Cc);
    }
}

// Deterministic final reduce: nblocks partial float2 pairs -> out[0], out[1].
__global__ __launch_bounds__(RTPB) void pml_reduce_kernel(
        const float* __restrict__ ws, float* __restrict__ out, int nblocks) {
    const int t = threadIdx.x;
    float loss = 0.0f, cnt = 0.0f;
    for (int b = t; b < nblocks; b += RTPB) {
        float2 p = reinterpret_cast<const float2*>(ws)[b];
        loss += p.x;
        cnt  += p.y;
    }
#pragma unroll
    for (int off = 32; off > 0; off >>= 1) {
        loss += __shfl_down(loss, off, 64);
        cnt  += __shfl_down(cnt,  off, 64);
    }
    __shared__ float sl[RTPB / 64], sc[RTPB / 64];
    const int wave = t >> 6;
    const int lane = t & 63;
    if (lane == 0) { sl[wave] = loss; sc[wave] = cnt; }
    __syncthreads();
    if (t == 0) {
        float L = 0.0f, Cc = 0.0f;
#pragma unroll
        for (int w = 0; w < RTPB / 64; ++w) { L += sl[w]; Cc += sc[w]; }
        out[0] = L;
        out[1] = Cc;
    }
}

extern "C" void kernel_launch(void* const* d_in, const int* in_sizes, int n_in,
                              void* d_out, int out_size, void* d_ws, size_t ws_size,
                              hipStream_t stream) {
    const float* o      = (const float*)d_in[0];
    const float* l      = (const float*)d_in[1];
    const int*   margin = (const int*)d_in[2];
    float*       out    = (float*)d_out;
    float*       ws     = (float*)d_ws;

    const int N = in_sizes[0] / (SAMPLE_S * SAMPLE_S);

    const int blocks_x = (int)(((long long)N + 4LL * TPB - 1) / (4LL * TPB));
    const int nblocks  = blocks_x * SAMPLE_S;

    hipLaunchKernelGGL(pml_main_kernel, dim3(blocks_x, SAMPLE_S), dim3(TPB), 0, stream,
                       o, l, margin, ws, N);
    hipLaunchKernelGGL(pml_reduce_kernel, dim3(1), dim3(RTPB), 0, stream,
                       ws, out, nblocks);
}